// Round 4
// baseline (303.158 us; speedup 1.0000x reference)
//
#include <hip/hip_runtime.h>
#include <hip/hip_bf16.h>
#include <stdint.h>

typedef float  f32x4  __attribute__((ext_vector_type(4)));
typedef float  f32x16 __attribute__((ext_vector_type(16)));
typedef unsigned int   u32x4 __attribute__((ext_vector_type(4)));
typedef unsigned short u16x4 __attribute__((ext_vector_type(4)));
typedef int    i32x4  __attribute__((ext_vector_type(4)));

__device__ inline unsigned short f2bf(float f) {
  unsigned int u = __builtin_bit_cast(unsigned int, f);
  u += 0x7fffu + ((u >> 16) & 1u);   // round-to-nearest-even
  return (unsigned short)(u >> 16);
}

__device__ inline void mfma32x32x16bf16(f32x16& acc, u32x4 a, u32x4 b) {
  asm volatile("v_mfma_f32_32x32x16_bf16 %0, %1, %2, %0"
               : "+v"(acc)
               : "v"(a), "v"(b));
}

__device__ inline void mfma16x16x32bf16(f32x4& acc, u32x4 a, u32x4 b) {
  asm volatile("v_mfma_f32_16x16x32_bf16 %0, %1, %2, %0"
               : "+v"(acc)
               : "v"(a), "v"(b));
}

__device__ inline void gload16(const unsigned short* src, char* ldsdst) {
  __builtin_amdgcn_global_load_lds(
      (const __attribute__((address_space(1))) void*)src,
      (__attribute__((address_space(3))) void*)ldsdst, 16, 0, 0);
}

// ======================================================================
// Fragment-ordered tiles for 32x32x16 MFMA (verified R3-R7).
// Tile (256 rows x 64 k) = 2048 chunks of 16B. Chunk c = s*512 + f*64 + lane
//   (s = k>>4, f = row>>5, lane = (row&31) + 32*((k>>3)&1)); 8 bf16/chunk.
// Each kh half (s pair) = contiguous 16 KB = one BK=32 subtile.
// ======================================================================

// prep_x: x fp32 [M][K] -> xb fragment-ordered bf16
__global__ __launch_bounds__(256) void prep_x(const float* __restrict__ x,
                                              unsigned short* __restrict__ xb,
                                              int K, int KT) {
  const int rb = blockIdx.x / KT;
  const int kt = blockIdx.x % KT;
  __shared__ unsigned short t[256 * 64];
  const int tid = threadIdx.x;
  const int klane = tid & 15;        // *4 floats along k
  const int rbase = tid >> 4;        // 0..15
  const float* src = x + (size_t)(rb * 256) * K + kt * 64;
  const int gw = klane >> 1, hw = klane & 1;   // 8-elem group, half
  for (int it = 0; it < 16; ++it) {
    int row = it * 16 + rbase;
    f32x4 v = *(const f32x4*)(src + (size_t)row * K + klane * 4);
    u16x4 h;
    h[0] = f2bf(v[0]); h[1] = f2bf(v[1]); h[2] = f2bf(v[2]); h[3] = f2bf(v[3]);
    *(u16x4*)&t[row * 64 + ((gw ^ (row & 7)) << 3) + hw * 4] = h;   // XOR-swizzled
  }
  __syncthreads();
  unsigned short* dst = xb + ((size_t)rb * KT + kt) * 16384;
  for (int j = 0; j < 8; ++j) {
    int c = j * 256 + tid;            // output-linear 16B chunk index
    int l = c & 63, f = (c >> 6) & 7, s = c >> 9;
    int row = f * 32 + (l & 31);
    int g   = (s * 2 + (l >> 5)) ^ (row & 7);
    u32x4 v = *(const u32x4*)&t[row * 64 + (g << 3)];
    *(u32x4*)(dst + (size_t)c * 8) = v;
  }
}

// prep_w: wq int32 [N][K], zp -> wb = bf16(w - zp) fragment-ordered
__global__ __launch_bounds__(256) void prep_w(const int* __restrict__ wq,
                                              const int* __restrict__ zp,
                                              unsigned short* __restrict__ wb,
                                              int K, int KT) {
  const int cb = blockIdx.x / KT;
  const int kt = blockIdx.x % KT;
  __shared__ unsigned short t[256 * 64];
  const int tid = threadIdx.x;
  const int klane = tid & 15;
  const int rbase = tid >> 4;
  const int* src = wq + (size_t)(cb * 256) * K + kt * 64;
  const int gw = klane >> 1, hw = klane & 1;
  for (int it = 0; it < 16; ++it) {
    int row = it * 16 + rbase;
    i32x4 v = *(const i32x4*)(src + (size_t)row * K + klane * 4);
    int z = zp[cb * 256 + row];
    u16x4 h;
    h[0] = f2bf((float)(v[0] - z)); h[1] = f2bf((float)(v[1] - z));
    h[2] = f2bf((float)(v[2] - z)); h[3] = f2bf((float)(v[3] - z));
    *(u16x4*)&t[row * 64 + ((gw ^ (row & 7)) << 3) + hw * 4] = h;
  }
  __syncthreads();
  unsigned short* dst = wb + ((size_t)cb * KT + kt) * 16384;
  for (int j = 0; j < 8; ++j) {
    int c = j * 256 + tid;
    int l = c & 63, f = (c >> 6) & 7, s = c >> 9;
    int row = f * 32 + (l & 31);
    int g   = (s * 2 + (l >> 5)) ^ (row & 7);
    u32x4 v = *(const u32x4*)&t[row * 64 + (g << 3)];
    *(u32x4*)(dst + (size_t)c * 8) = v;
  }
}

// ======================================================================
// 256x256 GEMM, 32x32x16 MFMA, 4-slot LDS ring, BK=32 subtiles.
// 512 thr = 8 waves (2M x 4N), per-wave 128x64 = 4x2 frags.
// Slot (32 KB) = A subtile 16 KB + B subtile 16 KB. Depth-3 prefetch.
//
// R11 (fixes R10 race): per-subtile two-phase schedule with the
// COLLECTIVE readiness point restored. vmcnt is per-wave, so ds_reads
// of a slot staged by all 8 waves must come AFTER {each wave waits its
// own vmcnt, then barrier}:
//   wait vmcnt(VM) -> B1 -> [reads s=0; STAGE(u+3); lgkm(0); 8 MFMA]
//   -> B2 -> [reads s=1; lgkm(0); 8 MFMA]
// RAW slot u: all stage(u) gloads drained collectively at B1. WAR slot
// u-1: every wave's phase-1 lgkm(0) precedes B1, so slot-(u-1) reads
// are all complete before STAGE(u+3) (issued after B1) overwrites it.
// B2 splits the subtile into two read-burst||MFMA windows so the two
// waves/SIMD alternate roles under setprio (T3 fine-interleave).
//
// vmcnt ledger (4 gloads per STAGE), wait at top of subtile u:
//   queue = [stage(u)4, stage(u+1)4, stage(u+2)4] = 12
//   -> vmcnt(8) drains stage(u). Tails: KT-3 -> 8, KT-2 -> 4, KT-1 -> 0.
// ======================================================================
__global__ __launch_bounds__(512, 2) void gemm_ring(
    const unsigned short* __restrict__ xb, const unsigned short* __restrict__ wb,
    const float* __restrict__ scale, const float* __restrict__ bias,
    float* __restrict__ out, int N, int KT) {   // KT = K/32 subtiles

  __shared__ unsigned short lds[65536];   // 128 KiB = 4 slots x 32 KB

  const int NB = N >> 8;
  // T1: XCD-aware swizzle (nwg % 8 == 0 guaranteed by launcher)
  const int nwg = gridDim.x;
  const int wg  = (blockIdx.x & 7) * (nwg >> 3) + (blockIdx.x >> 3);
  const int rb = wg / NB;
  const int cb = wg % NB;

  const int tid  = threadIdx.x;
  const int lane = tid & 63;
  const int wave = tid >> 6;
  const int wr = wave >> 2;        // 0..1  (M)
  const int wc = wave & 3;         // 0..3  (N)
  const int wr4 = wr * 4, wc2 = wc * 2;
  const int lane16 = lane * 16;

  // subtile u of A: xtb + u*8192 shorts (16 KB); same for B
  const unsigned short* xtb = xb + (size_t)rb * (KT >> 1) * 16384;
  const unsigned short* wtb = wb + (size_t)cb * (KT >> 1) * 16384;

  f32x16 acc[4][2] = {};

  auto STAGE = [&](int u) {
    const int slot = (u & 3) << 15;                 // 32 KB slots
    const unsigned short* as = xtb + (size_t)u * 8192;
    const unsigned short* bs = wtb + (size_t)u * 8192;
    char* da = (char*)lds + slot + wave * 2048;           // wave-uniform
    char* db = (char*)lds + slot + 16384 + wave * 2048;
    gload16(as + wave * 1024 + lane * 8, da);
    gload16(as + wave * 1024 + 512 + lane * 8, da + 1024);
    gload16(bs + wave * 1024 + lane * 8, db);
    gload16(bs + wave * 1024 + 512 + lane * 8, db + 1024);
  };

  auto LDA = [&](int slotb, int s, int m) -> u32x4 {
    return *(const u32x4*)((const char*)lds + slotb + s * 8192 +
                           (wr4 + m) * 1024 + lane16);
  };
  auto LDB = [&](int slotb, int s, int n) -> u32x4 {
    return *(const u32x4*)((const char*)lds + slotb + 16384 + s * 8192 +
                           (wc2 + n) * 1024 + lane16);
  };

#define BODY(U, VM, ST)                                                        \
  {                                                                            \
    const int u_ = (U);                                                        \
    const int sb = (u_ & 3) << 15;                                             \
    asm volatile("s_waitcnt vmcnt(" #VM ")" ::: "memory");                     \
    __builtin_amdgcn_s_barrier();  /* B1: slot u staged, slot u-1 consumed */  \
    /* ---------- phase 0 : k-slice s=0 ---------- */                          \
    {                                                                          \
      u32x4 b0 = LDB(sb, 0, 0), b1 = LDB(sb, 0, 1);                            \
      u32x4 a0 = LDA(sb, 0, 0), a1 = LDA(sb, 0, 1);                            \
      u32x4 a2 = LDA(sb, 0, 2), a3 = LDA(sb, 0, 3);                            \
      if (ST) STAGE(u_ + 3);                                                   \
      asm volatile("s_waitcnt lgkmcnt(0)" ::: "memory");                       \
      __builtin_amdgcn_s_setprio(1);                                           \
      mfma32x32x16bf16(acc[0][0], a0, b0);                                     \
      mfma32x32x16bf16(acc[0][1], a0, b1);                                     \
      mfma32x32x16bf16(acc[1][0], a1, b0);                                     \
      mfma32x32x16bf16(acc[1][1], a1, b1);                                     \
      mfma32x32x16bf16(acc[2][0], a2, b0);                                     \
      mfma32x32x16bf16(acc[2][1], a2, b1);                                     \
      mfma32x32x16bf16(acc[3][0], a3, b0);                                     \
      mfma32x32x16bf16(acc[3][1], a3, b1);                                     \
      __builtin_amdgcn_s_setprio(0);                                           \
    }                                                                          \
    __builtin_amdgcn_s_barrier();  /* B2: phase boundary */                    \
    /* ---------- phase 1 : k-slice s=1 ---------- */                          \
    {                                                                          \
      u32x4 b0 = LDB(sb, 1, 0), b1 = LDB(sb, 1, 1);                            \
      u32x4 a0 = LDA(sb, 1, 0), a1 = LDA(sb, 1, 1);                            \
      u32x4 a2 = LDA(sb, 1, 2), a3 = LDA(sb, 1, 3);                            \
      asm volatile("s_waitcnt lgkmcnt(0)" ::: "memory");                       \
      __builtin_amdgcn_s_setprio(1);                                           \
      mfma32x32x16bf16(acc[0][0], a0, b0);                                     \
      mfma32x32x16bf16(acc[0][1], a0, b1);                                     \
      mfma32x32x16bf16(acc[1][0], a1, b0);                                     \
      mfma32x32x16bf16(acc[1][1], a1, b1);                                     \
      mfma32x32x16bf16(acc[2][0], a2, b0);                                     \
      mfma32x32x16bf16(acc[2][1], a2, b1);                                     \
      mfma32x32x16bf16(acc[3][0], a3, b0);                                     \
      mfma32x32x16bf16(acc[3][1], a3, b1);                                     \
      __builtin_amdgcn_s_setprio(0);                                           \
    }                                                                          \
  }

  // -------- prologue: fill depth-3 --------
  STAGE(0); STAGE(1); STAGE(2);

  int u = 0;
  for (; u + 3 < KT; ++u) BODY(u, 8, true);   // stages 3..KT-1
  BODY(u, 8, false); ++u;                     // u = KT-3
  BODY(u, 4, false); ++u;                     // u = KT-2
  BODY(u, 0, false);                          // u = KT-1
#undef BODY

  // -------- epilogue: C/D layout col=lane&31, row=(reg&3)+8*(reg>>2)+4*(lane>>5)
  const int m0 = rb * 256 + wr * 128;
  const int n0 = cb * 256 + wc * 64;
  const int l31 = lane & 31, lhi = lane >> 5;
#pragma unroll
  for (int n = 0; n < 2; ++n) {
    const int col = n0 + n * 32 + l31;
    const float sc = scale[col];
    const float bi = bias[col];
#pragma unroll
    for (int m = 0; m < 4; ++m) {
      f32x16 v = acc[m][n];
      const int rowb = m0 + m * 32 + 4 * lhi;
#pragma unroll
      for (int q = 0; q < 4; ++q)
#pragma unroll
        for (int r = 0; r < 4; ++r)
          out[(size_t)(rowb + q * 8 + r) * N + col] = v[q * 4 + r] * sc + bi;
    }
  }
}

// ======================================================================
// Fallback (no workspace): 128x128 tile, in-loop dequant, 16x16x32
// ======================================================================
__global__ __launch_bounds__(256) void gemm_fallback(
    const float* __restrict__ x, const int* __restrict__ wq, const int* __restrict__ zp,
    const float* __restrict__ scale, const float* __restrict__ bias,
    float* __restrict__ out, int M, int N, int K) {

  __shared__ unsigned short Alds[128 * 32];
  __shared__ unsigned short Blds[128 * 32];

  const int tid = threadIdx.x;
  const int ntile = N / 128;
  const int m0 = (blockIdx.x / ntile) * 128, n0 = (blockIdx.x % ntile) * 128;
  const int lane = tid & 63;
  const int wave = tid >> 6;
  const int wr = wave >> 1, wc = wave & 1;
  const int lr = lane & 15, lhi = lane >> 4;
  f32x4 acc[4][4] = {};
  const int ar = tid >> 3, ac4 = tid & 7;

  for (int k0 = 0; k0 < K; k0 += 32) {
#pragma unroll
    for (int p = 0; p < 4; ++p) {
      int r = p * 32 + ar;
      i32x4 w = *(const i32x4*)(wq + (size_t)(n0 + r) * K + k0 + ac4 * 4);
      int z = zp[n0 + r];
      u16x4 h;
      h[0] = f2bf((float)(w[0] - z)); h[1] = f2bf((float)(w[1] - z));
      h[2] = f2bf((float)(w[2] - z)); h[3] = f2bf((float)(w[3] - z));
      *(u16x4*)&Blds[r * 32 + ac4 * 4] = h;
    }
#pragma unroll
    for (int p = 0; p < 4; ++p) {
      int r = p * 32 + ar;
      f32x4 v = *(const f32x4*)(x + (size_t)(m0 + r) * K + k0 + ac4 * 4);
      u16x4 h;
      h[0] = f2bf(v[0]); h[1] = f2bf(v[1]); h[2] = f2bf(v[2]); h[3] = f2bf(v[3]);
      *(u16x4*)&Alds[r * 32 + ac4 * 4] = h;
    }
    __syncthreads();
    u32x4 af[4], bf[4];
#pragma unroll
    for (int i = 0; i < 4; ++i) {
      af[i] = *(const u32x4*)&Alds[(wr * 64 + i * 16 + lr) * 32 + lhi * 8];
      bf[i] = *(const u32x4*)&Blds[(wc * 64 + i * 16 + lr) * 32 + lhi * 8];
    }
#pragma unroll
    for (int i = 0; i < 4; ++i)
#pragma unroll
      for (int j = 0; j < 4; ++j)
        mfma16x16x32bf16(acc[i][j], af[i], bf[j]);
    __syncthreads();
  }
  const int crow0 = m0 + wr * 64;
  const int ccol0 = n0 + wc * 64 + lr;
#pragma unroll
  for (int j = 0; j < 4; ++j) {
    int col = ccol0 + j * 16;
    float sc = scale[col], bi = bias[col];
#pragma unroll
    for (int i = 0; i < 4; ++i) {
      int row = crow0 + i * 16 + lhi * 4;
      f32x4 v = acc[i][j];
#pragma unroll
      for (int r = 0; r < 4; ++r)
        out[(size_t)(row + r) * N + col] = v[r] * sc + bi;
    }
  }
}

extern "C" void kernel_launch(void* const* d_in, const int* in_sizes, int n_in,
                              void* d_out, int out_size, void* d_ws, size_t ws_size,
                              hipStream_t stream) {
  const float* x     = (const float*)d_in[0];
  const int*   wq    = (const int*)d_in[1];
  const float* scale = (const float*)d_in[2];
  const int*   zp    = (const int*)d_in[3];
  const float* bias  = (const float*)d_in[4];
  float* out = (float*)d_out;

  const int DOUT = in_sizes[4];             // 4096
  const int DIN  = in_sizes[1] / DOUT;      // 4096
  const int M    = in_sizes[0] / DIN;       // 8192

  const size_t needX = (size_t)M * DIN * 2;
  const size_t needW = (size_t)DOUT * DIN * 2;

  const int nwg  = (M / 256) * (DOUT / 256);
  const int KT64 = DIN / 64;
  const int KT32 = DIN / 32;
  const bool shapes_ok = (M % 256 == 0) && (DOUT % 256 == 0) && (DIN % 64 == 0) &&
                         (nwg % 8 == 0) && (KT32 >= 8);

  if (shapes_ok && ws_size >= needX + needW) {
    unsigned short* xb = (unsigned short*)d_ws;
    unsigned short* wb = (unsigned short*)((char*)d_ws + needX);
    prep_x<<<(M / 256) * KT64, 256, 0, stream>>>(x, xb, DIN, KT64);
    prep_w<<<(DOUT / 256) * KT64, 256, 0, stream>>>(wq, zp, wb, DIN, KT64);
    gemm_ring<<<nwg, 512, 0, stream>>>(xb, wb, scale, bias, out, DOUT, KT32);
  } else {
    dim3 grid((M / 128) * (DOUT / 128));
    gemm_fallback<<<grid, 256, 0, stream>>>(x, wq, zp, scale, bias, out, M, DOUT, DIN);
  }
}

// Round 5
// 299.379 us; speedup vs baseline: 1.0126x; 1.0126x over previous
//
#include <hip/hip_runtime.h>
#include <hip/hip_bf16.h>
#include <stdint.h>

typedef float  f32x4  __attribute__((ext_vector_type(4)));
typedef float  f32x16 __attribute__((ext_vector_type(16)));
typedef unsigned int   u32x4 __attribute__((ext_vector_type(4)));
typedef unsigned short u16x4 __attribute__((ext_vector_type(4)));
typedef int    i32x4  __attribute__((ext_vector_type(4)));

__device__ inline unsigned short f2bf(float f) {
  unsigned int u = __builtin_bit_cast(unsigned int, f);
  u += 0x7fffu + ((u >> 16) & 1u);   // round-to-nearest-even
  return (unsigned short)(u >> 16);
}

__device__ inline void mfma32x32x16bf16(f32x16& acc, u32x4 a, u32x4 b) {
  asm volatile("v_mfma_f32_32x32x16_bf16 %0, %1, %2, %0"
               : "+v"(acc)
               : "v"(a), "v"(b));
}

__device__ inline void mfma16x16x32bf16(f32x4& acc, u32x4 a, u32x4 b) {
  asm volatile("v_mfma_f32_16x16x32_bf16 %0, %1, %2, %0"
               : "+v"(acc)
               : "v"(a), "v"(b));
}

__device__ inline void gload16(const unsigned short* src, char* ldsdst) {
  __builtin_amdgcn_global_load_lds(
      (const __attribute__((address_space(1))) void*)src,
      (__attribute__((address_space(3))) void*)ldsdst, 16, 0, 0);
}

// ======================================================================
// Fragment-ordered tiles for 32x32x16 MFMA (verified R3-R7).
// Tile (256 rows x 64 k) = 2048 chunks of 16B. Chunk c = s*512 + f*64 + lane
//   (s = k>>4, f = row>>5, lane = (row&31) + 32*((k>>3)&1)); 8 bf16/chunk.
// Each kh half (s pair) = contiguous 16 KB = one BK=32 subtile.
// ======================================================================

// prep_x: x fp32 [M][K] -> xb fragment-ordered bf16
__global__ __launch_bounds__(256) void prep_x(const float* __restrict__ x,
                                              unsigned short* __restrict__ xb,
                                              int K, int KT) {
  const int rb = blockIdx.x / KT;
  const int kt = blockIdx.x % KT;
  __shared__ unsigned short t[256 * 64];
  const int tid = threadIdx.x;
  const int klane = tid & 15;        // *4 floats along k
  const int rbase = tid >> 4;        // 0..15
  const float* src = x + (size_t)(rb * 256) * K + kt * 64;
  const int gw = klane >> 1, hw = klane & 1;   // 8-elem group, half
  for (int it = 0; it < 16; ++it) {
    int row = it * 16 + rbase;
    f32x4 v = *(const f32x4*)(src + (size_t)row * K + klane * 4);
    u16x4 h;
    h[0] = f2bf(v[0]); h[1] = f2bf(v[1]); h[2] = f2bf(v[2]); h[3] = f2bf(v[3]);
    *(u16x4*)&t[row * 64 + ((gw ^ (row & 7)) << 3) + hw * 4] = h;   // XOR-swizzled
  }
  __syncthreads();
  unsigned short* dst = xb + ((size_t)rb * KT + kt) * 16384;
  for (int j = 0; j < 8; ++j) {
    int c = j * 256 + tid;            // output-linear 16B chunk index
    int l = c & 63, f = (c >> 6) & 7, s = c >> 9;
    int row = f * 32 + (l & 31);
    int g   = (s * 2 + (l >> 5)) ^ (row & 7);
    u32x4 v = *(const u32x4*)&t[row * 64 + (g << 3)];
    *(u32x4*)(dst + (size_t)c * 8) = v;
  }
}

// prep_w: wq int32 [N][K], zp -> wb = bf16(w - zp) fragment-ordered
__global__ __launch_bounds__(256) void prep_w(const int* __restrict__ wq,
                                              const int* __restrict__ zp,
                                              unsigned short* __restrict__ wb,
                                              int K, int KT) {
  const int cb = blockIdx.x / KT;
  const int kt = blockIdx.x % KT;
  __shared__ unsigned short t[256 * 64];
  const int tid = threadIdx.x;
  const int klane = tid & 15;
  const int rbase = tid >> 4;
  const int* src = wq + (size_t)(cb * 256) * K + kt * 64;
  const int gw = klane >> 1, hw = klane & 1;
  for (int it = 0; it < 16; ++it) {
    int row = it * 16 + rbase;
    i32x4 v = *(const i32x4*)(src + (size_t)row * K + klane * 4);
    int z = zp[cb * 256 + row];
    u16x4 h;
    h[0] = f2bf((float)(v[0] - z)); h[1] = f2bf((float)(v[1] - z));
    h[2] = f2bf((float)(v[2] - z)); h[3] = f2bf((float)(v[3] - z));
    *(u16x4*)&t[row * 64 + ((gw ^ (row & 7)) << 3) + hw * 4] = h;
  }
  __syncthreads();
  unsigned short* dst = wb + ((size_t)cb * KT + kt) * 16384;
  for (int j = 0; j < 8; ++j) {
    int c = j * 256 + tid;
    int l = c & 63, f = (c >> 6) & 7, s = c >> 9;
    int row = f * 32 + (l & 31);
    int g   = (s * 2 + (l >> 5)) ^ (row & 7);
    u32x4 v = *(const u32x4*)&t[row * 64 + (g << 3)];
    *(u32x4*)(dst + (size_t)c * 8) = v;
  }
}

// ======================================================================
// 256x256 GEMM, 32x32x16 MFMA, 4-slot LDS ring, BK=32 subtiles.
// 512 thr = 8 waves (2M x 4N), per-wave 128x64 = 4x2 frags.
// Slot (32 KB) = A subtile 16 KB + B subtile 16 KB. Depth-3 prefetch.
//
// R12 (m201 readiness-one-early, on the R7 single-barrier skeleton):
// the vmcnt wait at the top of body u is vmcnt(4) = drains stage(u)
// AND stage(u+1). So after B(u), BOTH slots u and u+1 are collectively
// ready. Each body register-prefetches the s=0 fragments of subtile
// u+1 at its tail; body u+1's first 8 MFMAs start at barrier-exit with
// operands already in VGPRs (no post-barrier LDS round trip). s=1
// fragments are read inline (compiler-counted lgkm, as in R7).
//
// Correctness is placement-robust: any ds_read of slot u or u+1
// anywhere after B(u) is RAW-safe (readiness established before B(u)).
// WAR: slot (u+1)&3 is next rewritten by STAGE(u+5) in body u+2 —
// after the prefetch was consumed at the top of body u+1. STAGE(u+3)
// (writes slot (u-1)&3) is issued after B(u); every wave consumed its
// slot-(u-1) reads before reaching B(u). All LDS reads are plain C++
// (compiler inserts lgkm waits from register dependences — no manual
// lgkmcnt, no rule-18 hazard).
//
// vmcnt ledger (4 gloads per STAGE): at top of body u the queue is
// [stage(u+1)4, stage(u+2)4] = 8 -> vmcnt(4) drains stage(u+1)
// (issued 2 bodies ago, ~2000cyc slack). stage(u+2) stays in flight.
// Tails: u=KT-3 -> 4; u=KT-2 -> 0 (must drain stage(KT-1) for its
// prefetch); u=KT-1 -> 0 (no-op).
// ======================================================================
__global__ __launch_bounds__(512, 2) void gemm_ring(
    const unsigned short* __restrict__ xb, const unsigned short* __restrict__ wb,
    const float* __restrict__ scale, const float* __restrict__ bias,
    float* __restrict__ out, int N, int KT) {   // KT = K/32 subtiles

  __shared__ unsigned short lds[65536];   // 128 KiB = 4 slots x 32 KB

  const int NB = N >> 8;
  // T1: XCD-aware swizzle (nwg % 8 == 0 guaranteed by launcher)
  const int nwg = gridDim.x;
  const int wg  = (blockIdx.x & 7) * (nwg >> 3) + (blockIdx.x >> 3);
  const int rb = wg / NB;
  const int cb = wg % NB;

  const int tid  = threadIdx.x;
  const int lane = tid & 63;
  const int wave = tid >> 6;
  const int wr = wave >> 2;        // 0..1  (M)
  const int wc = wave & 3;         // 0..3  (N)
  const int wr4 = wr * 4, wc2 = wc * 2;
  const int lane16 = lane * 16;

  // subtile u of A: xtb + u*8192 shorts (16 KB); same for B
  const unsigned short* xtb = xb + (size_t)rb * (KT >> 1) * 16384;
  const unsigned short* wtb = wb + (size_t)cb * (KT >> 1) * 16384;

  f32x16 acc[4][2] = {};
  // s=0 fragment prefetch registers (filled one subtile ahead)
  u32x4 pa0, pa1, pa2, pa3, pb0, pb1;

  auto STAGE = [&](int u) {
    const int slot = (u & 3) << 15;                 // 32 KB slots
    const unsigned short* as = xtb + (size_t)u * 8192;
    const unsigned short* bs = wtb + (size_t)u * 8192;
    char* da = (char*)lds + slot + wave * 2048;           // wave-uniform
    char* db = (char*)lds + slot + 16384 + wave * 2048;
    gload16(as + wave * 1024 + lane * 8, da);
    gload16(as + wave * 1024 + 512 + lane * 8, da + 1024);
    gload16(bs + wave * 1024 + lane * 8, db);
    gload16(bs + wave * 1024 + 512 + lane * 8, db + 1024);
  };

  auto LDA = [&](int slotb, int s, int m) -> u32x4 {
    return *(const u32x4*)((const char*)lds + slotb + s * 8192 +
                           (wr4 + m) * 1024 + lane16);
  };
  auto LDB = [&](int slotb, int s, int n) -> u32x4 {
    return *(const u32x4*)((const char*)lds + slotb + 16384 + s * 8192 +
                           (wc2 + n) * 1024 + lane16);
  };

#define BODY(U, VM, ST, PF)                                                    \
  {                                                                            \
    const int u_ = (U);                                                        \
    const int sb  = (u_ & 3) << 15;                                            \
    const int sbn = ((u_ + 1) & 3) << 15;                                      \
    asm volatile("s_waitcnt vmcnt(" #VM ")" ::: "memory");                     \
    __builtin_amdgcn_s_barrier();                                              \
    if (ST) STAGE(u_ + 3);                                                     \
    __builtin_amdgcn_s_setprio(1);                                             \
    /* s=0: operands prefetched last body — matrix pipe starts now */          \
    mfma32x32x16bf16(acc[0][0], pa0, pb0);                                     \
    mfma32x32x16bf16(acc[0][1], pa0, pb1);                                     \
    mfma32x32x16bf16(acc[1][0], pa1, pb0);                                     \
    mfma32x32x16bf16(acc[1][1], pa1, pb1);                                     \
    mfma32x32x16bf16(acc[2][0], pa2, pb0);                                     \
    mfma32x32x16bf16(acc[2][1], pa2, pb1);                                     \
    mfma32x32x16bf16(acc[3][0], pa3, pb0);                                     \
    mfma32x32x16bf16(acc[3][1], pa3, pb1);                                     \
    /* s=1: inline reads, compiler interleaves with s=0 MFMAs */               \
    {                                                                          \
      u32x4 b0 = LDB(sb, 1, 0), b1 = LDB(sb, 1, 1);                            \
      u32x4 a0 = LDA(sb, 1, 0), a1 = LDA(sb, 1, 1);                            \
      u32x4 a2 = LDA(sb, 1, 2), a3 = LDA(sb, 1, 3);                            \
      mfma32x32x16bf16(acc[0][0], a0, b0);                                     \
      mfma32x32x16bf16(acc[0][1], a0, b1);                                     \
      mfma32x32x16bf16(acc[1][0], a1, b0);                                     \
      mfma32x32x16bf16(acc[1][1], a1, b1);                                     \
      mfma32x32x16bf16(acc[2][0], a2, b0);                                     \
      mfma32x32x16bf16(acc[2][1], a2, b1);                                     \
      mfma32x32x16bf16(acc[3][0], a3, b0);                                     \
      mfma32x32x16bf16(acc[3][1], a3, b1);                                     \
    }                                                                          \
    __builtin_amdgcn_s_setprio(0);                                             \
    if (PF) {                                                                  \
      pb0 = LDB(sbn, 0, 0); pb1 = LDB(sbn, 0, 1);                              \
      pa0 = LDA(sbn, 0, 0); pa1 = LDA(sbn, 0, 1);                              \
      pa2 = LDA(sbn, 0, 2); pa3 = LDA(sbn, 0, 3);                              \
    }                                                                          \
  }

  // -------- prologue: fill depth-3, then prefetch s0 of subtile 0 --------
  STAGE(0); STAGE(1); STAGE(2);
  asm volatile("s_waitcnt vmcnt(8)" ::: "memory");   // stage(0) complete
  __builtin_amdgcn_s_barrier();                      // collective: slot 0 ready
  pb0 = LDB(0, 0, 0); pb1 = LDB(0, 0, 1);
  pa0 = LDA(0, 0, 0); pa1 = LDA(0, 0, 1);
  pa2 = LDA(0, 0, 2); pa3 = LDA(0, 0, 3);

  int u = 0;
  for (; u + 3 < KT; ++u) BODY(u, 4, 1, 1);   // stages 3..KT-1
  BODY(u, 4, 0, 1); ++u;                      // u = KT-3
  BODY(u, 0, 0, 1); ++u;                      // u = KT-2 (drain for last pf)
  BODY(u, 0, 0, 0);                           // u = KT-1
#undef BODY

  // -------- epilogue: C/D layout col=lane&31, row=(reg&3)+8*(reg>>2)+4*(lane>>5)
  const int m0 = rb * 256 + wr * 128;
  const int n0 = cb * 256 + wc * 64;
  const int l31 = lane & 31, lhi = lane >> 5;
#pragma unroll
  for (int n = 0; n < 2; ++n) {
    const int col = n0 + n * 32 + l31;
    const float sc = scale[col];
    const float bi = bias[col];
#pragma unroll
    for (int m = 0; m < 4; ++m) {
      f32x16 v = acc[m][n];
      const int rowb = m0 + m * 32 + 4 * lhi;
#pragma unroll
      for (int q = 0; q < 4; ++q)
#pragma unroll
        for (int r = 0; r < 4; ++r)
          out[(size_t)(rowb + q * 8 + r) * N + col] = v[q * 4 + r] * sc + bi;
    }
  }
}

// ======================================================================
// Fallback (no workspace): 128x128 tile, in-loop dequant, 16x16x32
// ======================================================================
__global__ __launch_bounds__(256) void gemm_fallback(
    const float* __restrict__ x, const int* __restrict__ wq, const int* __restrict__ zp,
    const float* __restrict__ scale, const float* __restrict__ bias,
    float* __restrict__ out, int M, int N, int K) {

  __shared__ unsigned short Alds[128 * 32];
  __shared__ unsigned short Blds[128 * 32];

  const int tid = threadIdx.x;
  const int ntile = N / 128;
  const int m0 = (blockIdx.x / ntile) * 128, n0 = (blockIdx.x % ntile) * 128;
  const int lane = tid & 63;
  const int wave = tid >> 6;
  const int wr = wave >> 1, wc = wave & 1;
  const int lr = lane & 15, lhi = lane >> 4;
  f32x4 acc[4][4] = {};
  const int ar = tid >> 3, ac4 = tid & 7;

  for (int k0 = 0; k0 < K; k0 += 32) {
#pragma unroll
    for (int p = 0; p < 4; ++p) {
      int r = p * 32 + ar;
      i32x4 w = *(const i32x4*)(wq + (size_t)(n0 + r) * K + k0 + ac4 * 4);
      int z = zp[n0 + r];
      u16x4 h;
      h[0] = f2bf((float)(w[0] - z)); h[1] = f2bf((float)(w[1] - z));
      h[2] = f2bf((float)(w[2] - z)); h[3] = f2bf((float)(w[3] - z));
      *(u16x4*)&Blds[r * 32 + ac4 * 4] = h;
    }
#pragma unroll
    for (int p = 0; p < 4; ++p) {
      int r = p * 32 + ar;
      f32x4 v = *(const f32x4*)(x + (size_t)(m0 + r) * K + k0 + ac4 * 4);
      u16x4 h;
      h[0] = f2bf(v[0]); h[1] = f2bf(v[1]); h[2] = f2bf(v[2]); h[3] = f2bf(v[3]);
      *(u16x4*)&Alds[r * 32 + ac4 * 4] = h;
    }
    __syncthreads();
    u32x4 af[4], bf[4];
#pragma unroll
    for (int i = 0; i < 4; ++i) {
      af[i] = *(const u32x4*)&Alds[(wr * 64 + i * 16 + lr) * 32 + lhi * 8];
      bf[i] = *(const u32x4*)&Blds[(wc * 64 + i * 16 + lr) * 32 + lhi * 8];
    }
#pragma unroll
    for (int i = 0; i < 4; ++i)
#pragma unroll
      for (int j = 0; j < 4; ++j)
        mfma16x16x32bf16(acc[i][j], af[i], bf[j]);
    __syncthreads();
  }
  const int crow0 = m0 + wr * 64;
  const int ccol0 = n0 + wc * 64 + lr;
#pragma unroll
  for (int j = 0; j < 4; ++j) {
    int col = ccol0 + j * 16;
    float sc = scale[col], bi = bias[col];
#pragma unroll
    for (int i = 0; i < 4; ++i) {
      int row = crow0 + i * 16 + lhi * 4;
      f32x4 v = acc[i][j];
#pragma unroll
      for (int r = 0; r < 4; ++r)
        out[(size_t)(row + r) * N + col] = v[r] * sc + bi;
    }
  }
}

extern "C" void kernel_launch(void* const* d_in, const int* in_sizes, int n_in,
                              void* d_out, int out_size, void* d_ws, size_t ws_size,
                              hipStream_t stream) {
  const float* x     = (const float*)d_in[0];
  const int*   wq    = (const int*)d_in[1];
  const float* scale = (const float*)d_in[2];
  const int*   zp    = (const int*)d_in[3];
  const float* bias  = (const float*)d_in[4];
  float* out = (float*)d_out;

  const int DOUT = in_sizes[4];             // 4096
  const int DIN  = in_sizes[1] / DOUT;      // 4096
  const int M    = in_sizes[0] / DIN;       // 8192

  const size_t needX = (size_t)M * DIN * 2;
  const size_t needW = (size_t)DOUT * DIN * 2;

  const int nwg  = (M / 256) * (DOUT / 256);
  const int KT64 = DIN / 64;
  const int KT32 = DIN / 32;
  const bool shapes_ok = (M % 256 == 0) && (DOUT % 256 == 0) && (DIN % 64 == 0) &&
                         (nwg % 8 == 0) && (KT32 >= 8);

  if (shapes_ok && ws_size >= needX + needW) {
    unsigned short* xb = (unsigned short*)d_ws;
    unsigned short* wb = (unsigned short*)((char*)d_ws + needX);
    prep_x<<<(M / 256) * KT64, 256, 0, stream>>>(x, xb, DIN, KT64);
    prep_w<<<(DOUT / 256) * KT64, 256, 0, stream>>>(wq, zp, wb, DIN, KT64);
    gemm_ring<<<nwg, 512, 0, stream>>>(xb, wb, scale, bias, out, DOUT, KT32);
  } else {
    dim3 grid((M / 128) * (DOUT / 128));
    gemm_fallback<<<grid, 256, 0, stream>>>(x, wq, zp, scale, bias, out, M, DOUT, DIN);
  }
}

// Round 6
// 297.927 us; speedup vs baseline: 1.0176x; 1.0049x over previous
//
#include <hip/hip_runtime.h>
#include <hip/hip_bf16.h>
#include <stdint.h>

typedef float  f32x4  __attribute__((ext_vector_type(4)));
typedef float  f32x16 __attribute__((ext_vector_type(16)));
typedef unsigned int   u32x4 __attribute__((ext_vector_type(4)));
typedef unsigned short u16x4 __attribute__((ext_vector_type(4)));
typedef int    i32x4  __attribute__((ext_vector_type(4)));

__device__ inline unsigned short f2bf(float f) {
  unsigned int u = __builtin_bit_cast(unsigned int, f);
  u += 0x7fffu + ((u >> 16) & 1u);   // round-to-nearest-even
  return (unsigned short)(u >> 16);
}

__device__ inline void mfma32x32x16bf16(f32x16& acc, u32x4 a, u32x4 b) {
  asm volatile("v_mfma_f32_32x32x16_bf16 %0, %1, %2, %0"
               : "+v"(acc)
               : "v"(a), "v"(b));
}

__device__ inline void mfma16x16x32bf16(f32x4& acc, u32x4 a, u32x4 b) {
  asm volatile("v_mfma_f32_16x16x32_bf16 %0, %1, %2, %0"
               : "+v"(acc)
               : "v"(a), "v"(b));
}

__device__ inline void gload16(const unsigned short* src, char* ldsdst) {
  __builtin_amdgcn_global_load_lds(
      (const __attribute__((address_space(1))) void*)src,
      (__attribute__((address_space(3))) void*)ldsdst, 16, 0, 0);
}

// ======================================================================
// Fragment-ordered tiles for 32x32x16 MFMA (verified R3-R7).
// Tile (256 rows x 64 k) = 2048 chunks of 16B. Chunk c = s*512 + f*64 + lane
//   (s = k>>4, f = row>>5, lane = (row&31) + 32*((k>>3)&1)); 8 bf16/chunk.
// Each kh half (s pair) = contiguous 16 KB = one BK=32 subtile.
// ======================================================================

// prep_x: x fp32 [M][K] -> xb fragment-ordered bf16
__global__ __launch_bounds__(256) void prep_x(const float* __restrict__ x,
                                              unsigned short* __restrict__ xb,
                                              int K, int KT) {
  const int rb = blockIdx.x / KT;
  const int kt = blockIdx.x % KT;
  __shared__ unsigned short t[256 * 64];
  const int tid = threadIdx.x;
  const int klane = tid & 15;        // *4 floats along k
  const int rbase = tid >> 4;        // 0..15
  const float* src = x + (size_t)(rb * 256) * K + kt * 64;
  const int gw = klane >> 1, hw = klane & 1;   // 8-elem group, half
  for (int it = 0; it < 16; ++it) {
    int row = it * 16 + rbase;
    f32x4 v = *(const f32x4*)(src + (size_t)row * K + klane * 4);
    u16x4 h;
    h[0] = f2bf(v[0]); h[1] = f2bf(v[1]); h[2] = f2bf(v[2]); h[3] = f2bf(v[3]);
    *(u16x4*)&t[row * 64 + ((gw ^ (row & 7)) << 3) + hw * 4] = h;   // XOR-swizzled
  }
  __syncthreads();
  unsigned short* dst = xb + ((size_t)rb * KT + kt) * 16384;
  for (int j = 0; j < 8; ++j) {
    int c = j * 256 + tid;            // output-linear 16B chunk index
    int l = c & 63, f = (c >> 6) & 7, s = c >> 9;
    int row = f * 32 + (l & 31);
    int g   = (s * 2 + (l >> 5)) ^ (row & 7);
    u32x4 v = *(const u32x4*)&t[row * 64 + (g << 3)];
    *(u32x4*)(dst + (size_t)c * 8) = v;
  }
}

// prep_w: wq int32 [N][K], zp -> wb = bf16(w - zp) fragment-ordered
__global__ __launch_bounds__(256) void prep_w(const int* __restrict__ wq,
                                              const int* __restrict__ zp,
                                              unsigned short* __restrict__ wb,
                                              int K, int KT) {
  const int cb = blockIdx.x / KT;
  const int kt = blockIdx.x % KT;
  __shared__ unsigned short t[256 * 64];
  const int tid = threadIdx.x;
  const int klane = tid & 15;
  const int rbase = tid >> 4;
  const int* src = wq + (size_t)(cb * 256) * K + kt * 64;
  const int gw = klane >> 1, hw = klane & 1;
  for (int it = 0; it < 16; ++it) {
    int row = it * 16 + rbase;
    i32x4 v = *(const i32x4*)(src + (size_t)row * K + klane * 4);
    int z = zp[cb * 256 + row];
    u16x4 h;
    h[0] = f2bf((float)(v[0] - z)); h[1] = f2bf((float)(v[1] - z));
    h[2] = f2bf((float)(v[2] - z)); h[3] = f2bf((float)(v[3] - z));
    *(u16x4*)&t[row * 64 + ((gw ^ (row & 7)) << 3) + hw * 4] = h;
  }
  __syncthreads();
  unsigned short* dst = wb + ((size_t)cb * KT + kt) * 16384;
  for (int j = 0; j < 8; ++j) {
    int c = j * 256 + tid;
    int l = c & 63, f = (c >> 6) & 7, s = c >> 9;
    int row = f * 32 + (l & 31);
    int g   = (s * 2 + (l >> 5)) ^ (row & 7);
    u32x4 v = *(const u32x4*)&t[row * 64 + (g << 3)];
    *(u32x4*)(dst + (size_t)c * 8) = v;
  }
}

// ======================================================================
// 256x256 GEMM, 32x32x16 MFMA, 4-slot LDS ring, BK=64 BODIES (R13).
// 512 thr = 8 waves (2M x 4N), per-wave 128x64 = 4x2 frags.
//
// R13 change (vs R7): HALVE the sync frequency. Each body computes TWO
// BK=32 subtiles (32 MFMA/wave, 24 ds_reads) under a SINGLE
// {vmcnt + barrier}; the 4-slot ring acts as a pair-wise double buffer.
// Rationale from R7..R12 evidence: R11 showed one extra barrier/body
// costs ~+21 us (160-400 cyc each); all fine-phase (tighter-lockstep)
// variants were neutral or worse. So: fewer sync points, bigger free
// regions, more wave drift -> one wave's ds_reads overlap the sibling
// wave's MFMAs within the 2-subtile window.
//
// Body V (pair p = V&1, subtiles u0=2V slot (2V)&3, u1=2V+1):
//   wait vmcnt(0)   // drains STAGE(pair p) issued in body V-1 (~4700cyc
//                   // ago — semantic no-op, not a stall)
//   barrier         // collective: pair p ready; pair p^1 consumed
//   STAGE(2V+2); STAGE(2V+3)   // into pair p^1 (WAR safe: all waves
//                   // finished reading pair p^1 in body V-1, barrier passed)
//   compute u0 (16 MFMA, inline reads), compute u1 (16 MFMA)
// RAW: pair p drained by the vmcnt + made collective by the barrier.
// Last body stages nothing (peeled).
// ======================================================================
__global__ __launch_bounds__(512, 2) void gemm_ring(
    const unsigned short* __restrict__ xb, const unsigned short* __restrict__ wb,
    const float* __restrict__ scale, const float* __restrict__ bias,
    float* __restrict__ out, int N, int KT) {   // KT = K/32 subtiles

  __shared__ unsigned short lds[65536];   // 128 KiB = 4 slots x 32 KB

  const int NB = N >> 8;
  // T1: XCD-aware swizzle (nwg % 8 == 0 guaranteed by launcher)
  const int nwg = gridDim.x;
  const int wg  = (blockIdx.x & 7) * (nwg >> 3) + (blockIdx.x >> 3);
  const int rb = wg / NB;
  const int cb = wg % NB;

  const int tid  = threadIdx.x;
  const int lane = tid & 63;
  const int wave = tid >> 6;
  const int wr = wave >> 2;        // 0..1  (M)
  const int wc = wave & 3;         // 0..3  (N)
  const int wr4 = wr * 4, wc2 = wc * 2;
  const int lane16 = lane * 16;

  // subtile u of A: xtb + u*8192 shorts (16 KB); same for B
  const unsigned short* xtb = xb + (size_t)rb * (KT >> 1) * 16384;
  const unsigned short* wtb = wb + (size_t)cb * (KT >> 1) * 16384;

  f32x16 acc[4][2] = {};

  auto STAGE = [&](int u) {
    const int slot = (u & 3) << 15;                 // 32 KB slots
    const unsigned short* as = xtb + (size_t)u * 8192;
    const unsigned short* bs = wtb + (size_t)u * 8192;
    char* da = (char*)lds + slot + wave * 2048;           // wave-uniform
    char* db = (char*)lds + slot + 16384 + wave * 2048;
    gload16(as + wave * 1024 + lane * 8, da);
    gload16(as + wave * 1024 + 512 + lane * 8, da + 1024);
    gload16(bs + wave * 1024 + lane * 8, db);
    gload16(bs + wave * 1024 + 512 + lane * 8, db + 1024);
  };

  auto LDA = [&](int slotb, int s, int m) -> u32x4 {
    return *(const u32x4*)((const char*)lds + slotb + s * 8192 +
                           (wr4 + m) * 1024 + lane16);
  };
  auto LDB = [&](int slotb, int s, int n) -> u32x4 {
    return *(const u32x4*)((const char*)lds + slotb + 16384 + s * 8192 +
                           (wc2 + n) * 1024 + lane16);
  };

  // one BK=32 subtile's compute: 12 ds_reads + 16 MFMA, free-scheduled
#define SUBTILE(SB)                                                            \
  {                                                                            \
    const int sb_ = (SB);                                                      \
    __builtin_amdgcn_s_setprio(1);                                             \
    _Pragma("unroll")                                                          \
    for (int s = 0; s < 2; ++s) {                                              \
      u32x4 b0 = LDB(sb_, s, 0), b1 = LDB(sb_, s, 1);                          \
      _Pragma("unroll")                                                        \
      for (int m = 0; m < 4; ++m) {                                            \
        u32x4 a = LDA(sb_, s, m);                                              \
        mfma32x32x16bf16(acc[m][0], a, b0);                                    \
        mfma32x32x16bf16(acc[m][1], a, b1);                                    \
      }                                                                        \
    }                                                                          \
    __builtin_amdgcn_s_setprio(0);                                             \
  }

#define BODY(V, ST)                                                            \
  {                                                                            \
    const int v_ = (V);                                                        \
    const int u0 = v_ * 2, u1 = v_ * 2 + 1;                                    \
    asm volatile("s_waitcnt vmcnt(0)" ::: "memory");                           \
    __builtin_amdgcn_s_barrier();                                              \
    if (ST) { STAGE(u0 + 2); STAGE(u0 + 3); }                                  \
    SUBTILE((u0 & 3) << 15);                                                   \
    SUBTILE((u1 & 3) << 15);                                                   \
  }

  // -------- prologue: stage pair 0 --------
  STAGE(0); STAGE(1);

  const int NBODY = KT >> 1;
  int v = 0;
  for (; v + 1 < NBODY; ++v) BODY(v, true);
  BODY(v, false);                              // last body: no stage
#undef BODY
#undef SUBTILE

  // -------- epilogue: C/D layout col=lane&31, row=(reg&3)+8*(reg>>2)+4*(lane>>5)
  const int m0 = rb * 256 + wr * 128;
  const int n0 = cb * 256 + wc * 64;
  const int l31 = lane & 31, lhi = lane >> 5;
#pragma unroll
  for (int n = 0; n < 2; ++n) {
    const int col = n0 + n * 32 + l31;
    const float sc = scale[col];
    const float bi = bias[col];
#pragma unroll
    for (int m = 0; m < 4; ++m) {
      f32x16 v2 = acc[m][n];
      const int rowb = m0 + m * 32 + 4 * lhi;
#pragma unroll
      for (int q = 0; q < 4; ++q)
#pragma unroll
        for (int r = 0; r < 4; ++r)
          out[(size_t)(rowb + q * 8 + r) * N + col] = v2[q * 4 + r] * sc + bi;
    }
  }
}

// ======================================================================
// Fallback (no workspace): 128x128 tile, in-loop dequant, 16x16x32
// ======================================================================
__global__ __launch_bounds__(256) void gemm_fallback(
    const float* __restrict__ x, const int* __restrict__ wq, const int* __restrict__ zp,
    const float* __restrict__ scale, const float* __restrict__ bias,
    float* __restrict__ out, int M, int N, int K) {

  __shared__ unsigned short Alds[128 * 32];
  __shared__ unsigned short Blds[128 * 32];

  const int tid = threadIdx.x;
  const int ntile = N / 128;
  const int m0 = (blockIdx.x / ntile) * 128, n0 = (blockIdx.x % ntile) * 128;
  const int lane = tid & 63;
  const int wave = tid >> 6;
  const int wr = wave >> 1, wc = wave & 1;
  const int lr = lane & 15, lhi = lane >> 4;
  f32x4 acc[4][4] = {};
  const int ar = tid >> 3, ac4 = tid & 7;

  for (int k0 = 0; k0 < K; k0 += 32) {
#pragma unroll
    for (int p = 0; p < 4; ++p) {
      int r = p * 32 + ar;
      i32x4 w = *(const i32x4*)(wq + (size_t)(n0 + r) * K + k0 + ac4 * 4);
      int z = zp[n0 + r];
      u16x4 h;
      h[0] = f2bf((float)(w[0] - z)); h[1] = f2bf((float)(w[1] - z));
      h[2] = f2bf((float)(w[2] - z)); h[3] = f2bf((float)(w[3] - z));
      *(u16x4*)&Blds[r * 32 + ac4 * 4] = h;
    }
#pragma unroll
    for (int p = 0; p < 4; ++p) {
      int r = p * 32 + ar;
      f32x4 v = *(const f32x4*)(x + (size_t)(m0 + r) * K + k0 + ac4 * 4);
      u16x4 h;
      h[0] = f2bf(v[0]); h[1] = f2bf(v[1]); h[2] = f2bf(v[2]); h[3] = f2bf(v[3]);
      *(u16x4*)&Alds[r * 32 + ac4 * 4] = h;
    }
    __syncthreads();
    u32x4 af[4], bf[4];
#pragma unroll
    for (int i = 0; i < 4; ++i) {
      af[i] = *(const u32x4*)&Alds[(wr * 64 + i * 16 + lr) * 32 + lhi * 8];
      bf[i] = *(const u32x4*)&Blds[(wc * 64 + i * 16 + lr) * 32 + lhi * 8];
    }
#pragma unroll
    for (int i = 0; i < 4; ++i)
#pragma unroll
      for (int j = 0; j < 4; ++j)
        mfma16x16x32bf16(acc[i][j], af[i], bf[j]);
    __syncthreads();
  }
  const int crow0 = m0 + wr * 64;
  const int ccol0 = n0 + wc * 64 + lr;
#pragma unroll
  for (int j = 0; j < 4; ++j) {
    int col = ccol0 + j * 16;
    float sc = scale[col], bi = bias[col];
#pragma unroll
    for (int i = 0; i < 4; ++i) {
      int row = crow0 + i * 16 + lhi * 4;
      f32x4 v = acc[i][j];
#pragma unroll
      for (int r = 0; r < 4; ++r)
        out[(size_t)(row + r) * N + col] = v[r] * sc + bi;
    }
  }
}

extern "C" void kernel_launch(void* const* d_in, const int* in_sizes, int n_in,
                              void* d_out, int out_size, void* d_ws, size_t ws_size,
                              hipStream_t stream) {
  const float* x     = (const float*)d_in[0];
  const int*   wq    = (const int*)d_in[1];
  const float* scale = (const float*)d_in[2];
  const int*   zp    = (const int*)d_in[3];
  const float* bias  = (const float*)d_in[4];
  float* out = (float*)d_out;

  const int DOUT = in_sizes[4];             // 4096
  const int DIN  = in_sizes[1] / DOUT;      // 4096
  const int M    = in_sizes[0] / DIN;       // 8192

  const size_t needX = (size_t)M * DIN * 2;
  const size_t needW = (size_t)DOUT * DIN * 2;

  const int nwg  = (M / 256) * (DOUT / 256);
  const int KT64 = DIN / 64;
  const int KT32 = DIN / 32;
  const bool shapes_ok = (M % 256 == 0) && (DOUT % 256 == 0) && (DIN % 64 == 0) &&
                         (nwg % 8 == 0) && (KT32 >= 8) && (KT32 % 2 == 0);

  if (shapes_ok && ws_size >= needX + needW) {
    unsigned short* xb = (unsigned short*)d_ws;
    unsigned short* wb = (unsigned short*)((char*)d_ws + needX);
    prep_x<<<(M / 256) * KT64, 256, 0, stream>>>(x, xb, DIN, KT64);
    prep_w<<<(DOUT / 256) * KT64, 256, 0, stream>>>(wq, zp, wb, DIN, KT64);
    gemm_ring<<<nwg, 512, 0, stream>>>(xb, wb, scale, bias, out, DOUT, KT32);
  } else {
    dim3 grid((M / 128) * (DOUT / 128));
    gemm_fallback<<<grid, 256, 0, stream>>>(x, wq, zp, scale, bias, out, M, DOUT, DIN);
  }
}